// Round 8
// baseline (385.754 us; speedup 1.0000x reference)
//
#include <hip/hip_runtime.h>

typedef unsigned int   u32;
typedef unsigned short u16;

typedef _Float16 h2  __attribute__((ext_vector_type(2)));
typedef _Float16 h8  __attribute__((ext_vector_type(8)));
typedef float    f32x4 __attribute__((ext_vector_type(4)));
typedef u32      u32x4 __attribute__((ext_vector_type(4)));

#define M_TOK 128

__device__ __forceinline__ u16 f2h_(float f) {
    _Float16 h = (_Float16)f; return __builtin_bit_cast(u16, h);
}
__device__ __forceinline__ float h2f_(u16 b) {
    _Float16 h = __builtin_bit_cast(_Float16, b); return (float)h;
}
__device__ __forceinline__ void acc8(uint4 v, float* s) {
#pragma unroll
    for (int i = 0; i < 4; ++i) {
        u32 w = ((const u32*)&v)[i];
        s[2 * i]     += h2f_((u16)(w & 0xFFFF));
        s[2 * i + 1] += h2f_((u16)(w >> 16));
    }
}

// AWQ nibble order: n&7 = j sits at bit position ((j&1)<<4) | ((j>>1)<<2)
__constant__ int SHC[8] = {0, 16, 4, 20, 8, 24, 12, 28};

// ---------------------------------------------------------------------------
// pack_zs: (qz, sc) -> zs[g][n] u32 { lo16: fp16(-(1024+z)), hi16: fp16(sc) }
// ---------------------------------------------------------------------------
__launch_bounds__(256)
__global__ void pack_zs(const int* __restrict__ qz, const float* __restrict__ sc,
                        u32* __restrict__ zs, int qws, int scs, int Ncols, int total) {
    const int idx = blockIdx.x * 256 + threadIdx.x;
    if (idx >= total) return;
    const int g = idx / Ncols, n = idx - g * Ncols;
    const u32 d = (u32)qz[(size_t)g * qws + (n >> 3)];
    const u32 zj = (d >> SHC[n & 7]) & 15u;
    const u32 mz = 0xE400u | zj;                    // fp16 -(1024+z)
    const u16 sh = f2h_(sc[(size_t)g * scs + n]);
    zs[(size_t)g * Ncols + n] = mz | ((u32)sh << 16);
}

// ---------------------------------------------------------------------------
// pack_qwt: transpose qw [K][qws] (dword cols) -> qwt [cols][K] (col-major),
// taking a column slice [col0, col0+cols). Tiled 64k x 16c via LDS.
// ---------------------------------------------------------------------------
__launch_bounds__(256)
__global__ void pack_qwt(const int* __restrict__ qw, u32* __restrict__ qwt,
                         int qws, int col0, int K) {
    __shared__ u32 tile[16 * 64];                   // [c_local][k_local]
    const int t = threadIdx.x;
    const int k0 = blockIdx.x * 64, c0 = blockIdx.y * 16;
    const int r = t >> 2, cq = (t & 3) * 4;
    uint4 v = *(const uint4*)(qw + (size_t)(k0 + r) * qws + col0 + c0 + cq);
    tile[(cq + 0) * 64 + r] = v.x;
    tile[(cq + 1) * 64 + r] = v.y;
    tile[(cq + 2) * 64 + r] = v.z;
    tile[(cq + 3) * 64 + r] = v.w;
    __syncthreads();
    const int cl = t >> 4, kl = (t & 15) * 4;
    uint4 o = *(const uint4*)&tile[cl * 64 + kl];
    *(uint4*)(qwt + (size_t)(c0 + cl) * K + k0 + kl) = o;
}

// A-fragment-major layout: elem offset for logical (m, k):
//   kb=k/32, q=(k/8)&3, j=k&7, mt=m/16, l16=m&15
//   off = ((kb*8+mt)*64 + q*16 + l16)*8 + j    (fp16 elements)

// ---------------------------------------------------------------------------
// RMSNorm: one block per token row, fp32 in -> fp16 out in Afrag layout
// ---------------------------------------------------------------------------
__launch_bounds__(256)
__global__ void rmsnorm_k(const float* __restrict__ in, const float* __restrict__ w,
                          u16* __restrict__ out) {
    const int row = blockIdx.x;
    const float* x = in + (size_t)row * 4096;
    float ss = 0.f;
#pragma unroll
    for (int j = 0; j < 16; ++j) {
        float v = x[threadIdx.x + 256 * j];
        ss += v * v;
    }
#pragma unroll
    for (int off = 32; off > 0; off >>= 1) ss += __shfl_down(ss, off, 64);
    __shared__ float ws4[4];
    if ((threadIdx.x & 63) == 0) ws4[threadIdx.x >> 6] = ss;
    __syncthreads();
    float total = ws4[0] + ws4[1] + ws4[2] + ws4[3];
    float r = rsqrtf(total * (1.f / 4096.f) + 1e-6f);
    const int mt = row >> 4, l16 = row & 15;
#pragma unroll
    for (int c2 = 0; c2 < 2; ++c2) {
        int c = threadIdx.x * 2 + c2;
        int kb = c >> 2, qq = c & 3;
        u16 o8[8];
#pragma unroll
        for (int j = 0; j < 8; ++j) {
            int i = c * 8 + j;
            o8[j] = f2h_(x[i] * r * w[i]);
        }
        *(uint4*)(out + ((size_t)(kb * 8 + mt) * 64 + qq * 16 + l16) * 8) = *(const uint4*)o8;
    }
}

// ---------------------------------------------------------------------------
// AWQ GEMM v8: col-major qwt, direct-to-register dequant, ZERO LDS, no barriers.
// Block: BM=64 (mhalf=blockIdx.z) x BN=256 (4 waves x 64n), BK=32.
// Per lane: 4 nt-frags; raw = contiguous 32B (8 dwords, rows q*8..+7, col n>>3).
// Dequant: 8 shr + 4 perm + 4 and_or + 4 pk_add + 4 pk_mul per frag (exact R6 order).
// ---------------------------------------------------------------------------
struct Raw { uint4 a, b; };

__launch_bounds__(256, 2)
__global__ void gemm8(const u16* __restrict__ A, const u32* __restrict__ zs,
                      const u32* __restrict__ qwt, u16* __restrict__ part,
                      int K, int kchunk, int Nz, int Np) {
    const int tid = threadIdx.x, w = tid >> 6, lane = tid & 63;
    const int q = lane >> 4, l16 = lane & 15;
    const int n0w = blockIdx.x * 256 + w * 64;
    const int mh  = blockIdx.z;
    const int sk = blockIdx.y, kc0 = sk * kchunk, kend = min(kc0 + kchunk, K);
    const int j = l16 & 7;
    const u32 sh = (u32)(((j & 1) << 4) | ((j >> 1) << 2));

    const u32* qp[4];
#pragma unroll
    for (int nt = 0; nt < 4; ++nt)
        qp[nt] = qwt + (size_t)((n0w + nt * 16 + l16) >> 3) * K + q * 8;
    const u32* zsl = zs + n0w + l16;
    const u16* Ala = A + lane * 8 + (size_t)mh * 4 * 512;

    f32x4 acc[4][4] = {};
    h2 mzv[4], s2v[4];
    u32 zq[4];

    auto ldz = [&](int g) {
#pragma unroll
        for (int nt = 0; nt < 4; ++nt) zq[nt] = zsl[(size_t)g * Nz + nt * 16];
    };
    auto cvtz = [&]() {
#pragma unroll
        for (int nt = 0; nt < 4; ++nt) {
            mzv[nt] = __builtin_bit_cast(h2, __builtin_amdgcn_perm(zq[nt], zq[nt], 0x01000100u));
            s2v[nt] = __builtin_bit_cast(h2, __builtin_amdgcn_perm(zq[nt], zq[nt], 0x03020302u));
        }
    };
    auto ldraw = [&](int k, Raw* r) {
#pragma unroll
        for (int nt = 0; nt < 4; ++nt) {
            r[nt].a = *(const uint4*)(qp[nt] + k);
            r[nt].b = *(const uint4*)(qp[nt] + k + 4);
        }
    };
    auto lda = [&](int k, uint4* a) {
        const int kb = k >> 5;
#pragma unroll
        for (int mt = 0; mt < 4; ++mt)
            a[mt] = *(const uint4*)(Ala + (size_t)(kb * 8 + mt) * 512);
    };
    auto deq = [&](const Raw& r, int nt) -> h8 {
        u32 t0 = r.a.x >> sh, t1 = r.a.y >> sh, t2 = r.a.z >> sh, t3 = r.a.w >> sh;
        u32 t4 = r.b.x >> sh, t5 = r.b.y >> sh, t6 = r.b.z >> sh, t7 = r.b.w >> sh;
        u32x4 o;
        auto em = [&](u32 te, u32 to) -> u32 {
            u32 u = (__builtin_amdgcn_perm(to, te, 0x00040000u) & 0x000F000Fu) | 0x64006400u;
            h2 v = (__builtin_bit_cast(h2, u) + mzv[nt]) * s2v[nt];
            return __builtin_bit_cast(u32, v);
        };
        o.x = em(t0, t1); o.y = em(t2, t3); o.z = em(t4, t5); o.w = em(t6, t7);
        return __builtin_bit_cast(h8, o);
    };

    Raw rA[4], rB[4];
    uint4 av[4];

    // ---- prologue ----
    ldz(kc0 >> 7);
    ldraw(kc0, rA);
    if (kc0 + 32 < kend) ldraw(kc0 + 32, rB);
    cvtz();

    auto body = [&](int k0, Raw* rcur) {
        const bool kn1 = (k0 + 32) < kend, kn2 = (k0 + 64) < kend;
        lda(k0, av);                                   // current-iter A (L1/L2-warm)
        if (kn2 && (((k0 + 64) & 127) == 0)) ldz((k0 + 64) >> 7);
#pragma unroll
        for (int nt = 0; nt < 4; ++nt) {
            h8 b = deq(rcur[nt], nt);
            if (kn2) {                                  // reload this slot for k0+64
                rcur[nt].a = *(const uint4*)(qp[nt] + k0 + 64);
                rcur[nt].b = *(const uint4*)(qp[nt] + k0 + 68);
            }
#pragma unroll
            for (int mt = 0; mt < 4; ++mt)
                acc[mt][nt] = __builtin_amdgcn_mfma_f32_16x16x32_f16(
                    __builtin_bit_cast(h8, av[mt]), b, acc[mt][nt], 0, 0, 0);
        }
        if (kn1 && (((k0 + 32) & 127) == 0)) cvtz();
    };

    for (int k0 = kc0;;) {
        body(k0, rA);
        k0 += 32; if (k0 >= kend) break;
        body(k0, rB);
        k0 += 32; if (k0 >= kend) break;
    }

    // ---- epilogue: fp16 partial store ----
    u16* pp = part + (size_t)sk * M_TOK * Np;
#pragma unroll
    for (int mt = 0; mt < 4; ++mt)
#pragma unroll
        for (int nt = 0; nt < 4; ++nt) {
            const int n = n0w + nt * 16 + l16;
#pragma unroll
            for (int r = 0; r < 4; ++r) {
                const int m = mh * 64 + mt * 16 + q * 4 + r;
                pp[(size_t)m * Np + n] = f2h_(acc[mt][nt][r]);
            }
        }
}

// ---------------------------------------------------------------------------
// Reduce SK fp16 partial planes [sk][128][4096] -> fp16 in Afrag layout
// ---------------------------------------------------------------------------
__launch_bounds__(256)
__global__ void reduce_to_afrag(const u16* __restrict__ part, u16* __restrict__ out,
                                int SK) {
    const int idx = blockIdx.x * 256 + threadIdx.x;
    const int m = idx >> 9, c = idx & 511;
    float s[8] = {};
    for (int k = 0; k < SK; ++k)
        acc8(*(const uint4*)(part + (size_t)k * 524288 + (size_t)m * 4096 + c * 8), s);
    const int kb = c >> 2, qq = c & 3, mt = m >> 4, l16 = m & 15;
    u16 o8[8];
#pragma unroll
    for (int j = 0; j < 8; ++j) o8[j] = f2h_(s[j]);
    *(uint4*)(out + ((size_t)(kb * 8 + mt) * 64 + qq * 16 + l16) * 8) = *(const uint4*)o8;
}

__launch_bounds__(256)
__global__ void reduce_add_f32(const u16* __restrict__ part, const float* __restrict__ resin,
                               float* __restrict__ out, int SK) {
    const int idx = blockIdx.x * 256 + threadIdx.x;
    const size_t base = (size_t)idx * 8;
    float s[8];
    *(float4*)&s[0] = *(const float4*)(resin + base);
    *(float4*)&s[4] = *(const float4*)(resin + base + 4);
    for (int k = 0; k < SK; ++k)
        acc8(*(const uint4*)(part + (size_t)k * 524288 + base), s);
    *(float4*)(out + base)     = *(const float4*)&s[0];
    *(float4*)(out + base + 4) = *(const float4*)&s[4];
}

// Reduce gate partials [6][128][11008] -> gate16 row-major fp16
__launch_bounds__(256)
__global__ void reduce_gate(const u16* __restrict__ part, u16* __restrict__ gate16) {
    const int idx = blockIdx.x * 256 + threadIdx.x;   // 0..176127
    const size_t base = (size_t)idx * 8;
    float s[8] = {};
    for (int k = 0; k < 6; ++k)
        acc8(*(const uint4*)(part + (size_t)k * 1409024 + base), s);
    u16 o8[8];
#pragma unroll
    for (int j = 0; j < 8; ++j) o8[j] = f2h_(s[j]);
    *(uint4*)(gate16 + base) = *(const uint4*)o8;
}

// silu(gate16) * reduce(up partials [6][128][11008]) -> act fp16 Afrag (K=11008)
__launch_bounds__(256)
__global__ void silu8(const u16* __restrict__ part, const u16* __restrict__ gate16,
                      u16* __restrict__ act) {
    const int idx = blockIdx.x * 256 + threadIdx.x;
    const int m = idx / 1376, c = idx - m * 1376;
    const int nb = c * 8;
    const size_t base = (size_t)m * 11008 + nb;
    float g[8] = {}, u[8] = {};
    acc8(*(const uint4*)(gate16 + base), g);
    for (int k = 0; k < 6; ++k)
        acc8(*(const uint4*)(part + (size_t)k * 1409024 + base), u);
    const int kb = nb >> 5, qq = (nb >> 3) & 3, mt = m >> 4, l16 = m & 15;
    u16 o8[8];
#pragma unroll
    for (int j = 0; j < 8; ++j) {
        float a = g[j] / (1.f + __expf(-g[j])) * u[j];
        o8[j] = f2h_(a);
    }
    *(uint4*)(act + ((size_t)(kb * 8 + mt) * 64 + qq * 16 + l16) * 8) = *(const uint4*)o8;
}

// ---------------------------------------------------------------------------
extern "C" void kernel_launch(void* const* d_in, const int* in_sizes, int n_in,
                              void* d_out, int out_size, void* d_ws, size_t ws_size,
                              hipStream_t stream) {
    const float* x      = (const float*)d_in[0];
    const float* ln1_w  = (const float*)d_in[1];
    const float* ln2_w  = (const float*)d_in[2];
    const int*   qkv_qw = (const int*)d_in[3];
    const int*   qkv_qz = (const int*)d_in[4];
    const float* qkv_sc = (const float*)d_in[5];
    const int*   o_qw   = (const int*)d_in[6];
    const int*   o_qz   = (const int*)d_in[7];
    const float* o_sc   = (const float*)d_in[8];
    const int*   gu_qw  = (const int*)d_in[9];
    const int*   gu_qz  = (const int*)d_in[10];
    const float* gu_sc  = (const float*)d_in[11];
    const int*   dn_qw  = (const int*)d_in[12];
    const int*   dn_qz  = (const int*)d_in[13];
    const float* dn_sc  = (const float*)d_in[14];
    float* out = (float*)d_out;

    // ws layout (~51.1 MB)
    char* ws = (char*)d_ws;
    u16*   pbuf   = (u16*)(ws);                 // partials: 16.9 MB max
    u32*   qwt    = (u32*)(ws + 16908288);      // transposed qw slice: 22.5 MB max
    u32*   zsb    = (u32*)(ws + 39452672);      // 2.82 MB
    u16*   gate16 = (u16*)(ws + 42270720);      // 2.82 MB
    u16*   act    = (u16*)(ws + 45088768);      // 2.82 MB (Afrag, K=11008)
    float* res2   = (float*)(ws + 47906816);    // 2 MB
    u16*   slot   = (u16*)(ws + 50003968);      // 1 MB (Afrag, K=4096)

    // h1 = rmsnorm(x, ln1) -> Afrag
    rmsnorm_k<<<128, 256, 0, stream>>>(x, ln1_w, slot);

    // q = h1 @ Wqkv[:, :4096]
    pack_zs<<<512, 256, 0, stream>>>(qkv_qz, qkv_sc, zsb, 1536, 12288, 4096, 131072);
    pack_qwt<<<dim3(64, 32), 256, 0, stream>>>(qkv_qw, qwt, 1536, 0, 4096);
    gemm8<<<dim3(16, 16, 2), 256, 0, stream>>>(slot, zsb, qwt, pbuf, 4096, 256, 4096, 4096);
    reduce_to_afrag<<<256, 256, 0, stream>>>(pbuf, slot, 16);

    // attn = q @ Wo ; res2 = x + attn
    pack_zs<<<512, 256, 0, stream>>>(o_qz, o_sc, zsb, 512, 4096, 4096, 131072);
    pack_qwt<<<dim3(64, 32), 256, 0, stream>>>(o_qw, qwt, 512, 0, 4096);
    gemm8<<<dim3(16, 16, 2), 256, 0, stream>>>(slot, zsb, qwt, pbuf, 4096, 256, 4096, 4096);
    reduce_add_f32<<<256, 256, 0, stream>>>(pbuf, x, res2, 16);

    // h2 = rmsnorm(res2, ln2) -> Afrag
    rmsnorm_k<<<128, 256, 0, stream>>>(res2, ln2_w, slot);

    // gate = h2 @ Wgu[:, :11008]
    pack_zs<<<2752, 256, 0, stream>>>(gu_qz, gu_sc, zsb, 2752, 22016, 22016, 704512);
    pack_qwt<<<dim3(64, 86), 256, 0, stream>>>(gu_qw, qwt, 2752, 0, 4096);
    gemm8<<<dim3(43, 6, 2), 256, 0, stream>>>(slot, zsb, qwt, pbuf, 4096, 704, 22016, 11008);
    reduce_gate<<<688, 256, 0, stream>>>(pbuf, gate16);

    // up = h2 @ Wgu[:, 11008:] ; act = silu(gate)*up
    pack_qwt<<<dim3(64, 86), 256, 0, stream>>>(gu_qw, qwt, 2752, 1376, 4096);
    gemm8<<<dim3(43, 6, 2), 256, 0, stream>>>(slot, zsb + 11008, qwt, pbuf, 4096, 704, 22016, 11008);
    silu8<<<688, 256, 0, stream>>>(pbuf, gate16, act);

    // down = act @ Wdn ; out = res2 + down
    pack_zs<<<1376, 256, 0, stream>>>(dn_qz, dn_sc, zsb, 512, 4096, 4096, 352256);
    pack_qwt<<<dim3(172, 32), 256, 0, stream>>>(dn_qw, qwt, 512, 0, 11008);
    gemm8<<<dim3(16, 16, 2), 256, 0, stream>>>(act, zsb, qwt, pbuf, 11008, 704, 4096, 4096);
    reduce_add_f32<<<256, 256, 0, stream>>>(pbuf, res2, out, 16);
}